// Round 3
// baseline (13228.934 us; speedup 1.0000x reference)
//
#include <hip/hip_runtime.h>
#include <math.h>

#define L_PER_B 32768
#define M_TOK   65536

// ---------------------------------------------------------------------------
// x [B, C, 32,32,32]  ->  h [B, L, C]   (tokens-channels)
// ---------------------------------------------------------------------------
__global__ __launch_bounds__(256) void k_nchw_to_nlc(const float* __restrict__ x,
                                                     float* __restrict__ h)
{
    __shared__ float t[32][33];
    const int lt = blockIdx.x * 32;      // token tile
    const int ct = blockIdx.y * 32;      // channel tile
    const int b  = blockIdx.z;
    const int li = threadIdx.x & 31;
    const int cg = threadIdx.x >> 5;     // 0..7
    const float* xb = x + (size_t)b * 256 * L_PER_B;
    #pragma unroll
    for (int r = 0; r < 4; ++r) {
        const int c = cg + 8 * r;
        t[c][li] = xb[(size_t)(ct + c) * L_PER_B + lt + li];
    }
    __syncthreads();
    float* hb = h + (size_t)b * L_PER_B * 256;
    #pragma unroll
    for (int r = 0; r < 4; ++r) {
        const int lrow = cg + 8 * r;
        hb[(size_t)(lt + lrow) * 256 + ct + li] = t[li][lrow];
    }
}

// ---------------------------------------------------------------------------
// LayerNorm over C=256, one wave per row (4 rows per 256-thread block)
// ---------------------------------------------------------------------------
__global__ __launch_bounds__(256) void k_ln(const float* __restrict__ x,
                                            const float* __restrict__ g,
                                            const float* __restrict__ b,
                                            float* __restrict__ out)
{
    const int row  = blockIdx.x * 4 + (threadIdx.x >> 6);
    const int lane = threadIdx.x & 63;
    const float4 v = *(const float4*)(x + (size_t)row * 256 + lane * 4);
    float s  = v.x + v.y + v.z + v.w;
    float s2 = v.x * v.x + v.y * v.y + v.z * v.z + v.w * v.w;
    #pragma unroll
    for (int o = 32; o > 0; o >>= 1) {
        s  += __shfl_xor(s,  o, 64);
        s2 += __shfl_xor(s2, o, 64);
    }
    const float mu = s * 0.00390625f;
    const float rs = rsqrtf(fmaxf(s2 * 0.00390625f - mu * mu, 0.f) + 1e-5f);
    const float4 gv = *(const float4*)(g + lane * 4);
    const float4 bv = *(const float4*)(b + lane * 4);
    float4 o4;
    o4.x = (v.x - mu) * rs * gv.x + bv.x;
    o4.y = (v.y - mu) * rs * gv.y + bv.y;
    o4.z = (v.z - mu) * rs * gv.z + bv.z;
    o4.w = (v.w - mu) * rs * gv.w + bv.w;
    *(float4*)(out + (size_t)row * 256 + lane * 4) = o4;
}

// ---------------------------------------------------------------------------
// LN row statistics only: stats[2r] = mean, stats[2r+1] = rstd
// ---------------------------------------------------------------------------
__global__ __launch_bounds__(256) void k_lnstats(const float* __restrict__ x,
                                                 float* __restrict__ stats)
{
    const int row  = blockIdx.x * 4 + (threadIdx.x >> 6);
    const int lane = threadIdx.x & 63;
    const float4 v = *(const float4*)(x + (size_t)row * 256 + lane * 4);
    float s  = v.x + v.y + v.z + v.w;
    float s2 = v.x * v.x + v.y * v.y + v.z * v.z + v.w * v.w;
    #pragma unroll
    for (int o = 32; o > 0; o >>= 1) {
        s  += __shfl_xor(s,  o, 64);
        s2 += __shfl_xor(s2, o, 64);
    }
    if (lane == 0) {
        const float mu = s * 0.00390625f;
        const float rs = rsqrtf(fmaxf(s2 * 0.00390625f - mu * mu, 0.f) + 1e-5f);
        stats[2 * row]     = mu;
        stats[2 * row + 1] = rs;
    }
}

// ---------------------------------------------------------------------------
// fp32 GEMM: out[M,N] = epi(An[M,K] @ W[K,N] + bias)
// EPI 0: bias   1: bias+GELU(exact)   2: bias+residual   3: bias+ReLU,
//        store transposed to NCDHW output [B, C, L]
// LNA: A-tile load applies layernorm using stats[2r],stats[2r+1] and lg/lb[k]
// WT : W is stored [N][K] (row-major weights, e.g. pw_w) -> read transposed
// BM=BN=128, BK=16, 256 threads, 8x8 per thread.
// ---------------------------------------------------------------------------
template<int EPI, bool LNA, bool WT>
__global__ __launch_bounds__(256) void k_gemm(const float* __restrict__ A,
                                              const float* __restrict__ W,
                                              const float* __restrict__ bias,
                                              const float* resid,   // may alias out
                                              float* out,
                                              int N, int K,
                                              const float* __restrict__ stats,
                                              const float* __restrict__ lg,
                                              const float* __restrict__ lb)
{
    __shared__ float As[16][132];   // A tile stored transposed: As[k][m]
    __shared__ float Bs[16][128];
    const int tid   = threadIdx.x;
    const int m_blk = blockIdx.y * 128;
    const int n_blk = blockIdx.x * 128;
    const int mg = (tid & 15) * 8;
    const int ng = (tid >> 4) * 8;
    float acc[8][8];
    #pragma unroll
    for (int i = 0; i < 8; ++i)
        #pragma unroll
        for (int j = 0; j < 8; ++j) acc[i][j] = 0.f;

    for (int k0 = 0; k0 < K; k0 += 16) {
        #pragma unroll
        for (int u = 0; u < 2; ++u) {
            const int f   = tid + u * 256;       // 0..511
            const int row = f >> 2;              // 0..127
            const int kq  = (f & 3) << 2;        // 0,4,8,12
            float4 a = *(const float4*)(A + (size_t)(m_blk + row) * K + k0 + kq);
            if constexpr (LNA) {
                const float mu  = stats[2 * (m_blk + row)];
                const float rsd = stats[2 * (m_blk + row) + 1];
                const float4 gk = *(const float4*)(lg + k0 + kq);
                const float4 bk = *(const float4*)(lb + k0 + kq);
                a.x = (a.x - mu) * rsd * gk.x + bk.x;
                a.y = (a.y - mu) * rsd * gk.y + bk.y;
                a.z = (a.z - mu) * rsd * gk.z + bk.z;
                a.w = (a.w - mu) * rsd * gk.w + bk.w;
            }
            As[kq + 0][row] = a.x;
            As[kq + 1][row] = a.y;
            As[kq + 2][row] = a.z;
            As[kq + 3][row] = a.w;
        }
        #pragma unroll
        for (int u = 0; u < 2; ++u) {
            const int f = tid + u * 256;
            if constexpr (!WT) {
                const int kk = f >> 5;               // 0..15
                const int nq = (f & 31) << 2;        // 0..124
                *(float4*)&Bs[kk][nq] = *(const float4*)(W + (size_t)(k0 + kk) * N + n_blk + nq);
            } else {
                const int n  = f >> 2;               // 0..127
                const int kq = (f & 3) << 2;
                const float4 wv = *(const float4*)(W + (size_t)(n_blk + n) * K + k0 + kq);
                Bs[kq + 0][n] = wv.x;
                Bs[kq + 1][n] = wv.y;
                Bs[kq + 2][n] = wv.z;
                Bs[kq + 3][n] = wv.w;
            }
        }
        __syncthreads();
        #pragma unroll
        for (int kk = 0; kk < 16; ++kk) {
            const float4 a0 = *(const float4*)&As[kk][mg];
            const float4 a1 = *(const float4*)&As[kk][mg + 4];
            const float4 b0 = *(const float4*)&Bs[kk][ng];
            const float4 b1 = *(const float4*)&Bs[kk][ng + 4];
            const float am[8] = {a0.x, a0.y, a0.z, a0.w, a1.x, a1.y, a1.z, a1.w};
            const float bn[8] = {b0.x, b0.y, b0.z, b0.w, b1.x, b1.y, b1.z, b1.w};
            #pragma unroll
            for (int i = 0; i < 8; ++i)
                #pragma unroll
                for (int j = 0; j < 8; ++j)
                    acc[i][j] = fmaf(am[i], bn[j], acc[i][j]);
        }
        __syncthreads();
    }

    if constexpr (EPI == 3) {
        const int m0    = m_blk + mg;
        const int batch = m0 >> 15;          // / 32768
        const int l     = m0 & 32767;
        float* ob = out + (size_t)batch * (256 * (size_t)L_PER_B) + l;
        #pragma unroll
        for (int j = 0; j < 8; ++j) {
            const int c = n_blk + ng + j;
            const float bj = bias[c];
            float4 v0, v1;
            v0.x = fmaxf(acc[0][j] + bj, 0.f); v0.y = fmaxf(acc[1][j] + bj, 0.f);
            v0.z = fmaxf(acc[2][j] + bj, 0.f); v0.w = fmaxf(acc[3][j] + bj, 0.f);
            v1.x = fmaxf(acc[4][j] + bj, 0.f); v1.y = fmaxf(acc[5][j] + bj, 0.f);
            v1.z = fmaxf(acc[6][j] + bj, 0.f); v1.w = fmaxf(acc[7][j] + bj, 0.f);
            *(float4*)(ob + (size_t)c * L_PER_B)     = v0;
            *(float4*)(ob + (size_t)c * L_PER_B + 4) = v1;
        }
    } else {
        float bj[8];
        #pragma unroll
        for (int j = 0; j < 8; ++j) bj[j] = bias[n_blk + ng + j];
        #pragma unroll
        for (int i = 0; i < 8; ++i) {
            const size_t r = (size_t)(m_blk + mg + i);
            float v[8];
            #pragma unroll
            for (int j = 0; j < 8; ++j) v[j] = acc[i][j] + bj[j];
            if constexpr (EPI == 1) {
                #pragma unroll
                for (int j = 0; j < 8; ++j)
                    v[j] = 0.5f * v[j] * (1.f + erff(v[j] * 0.70710678118654752f));
            }
            if constexpr (EPI == 2) {
                const float4 r0 = *(const float4*)(resid + r * N + n_blk + ng);
                const float4 r1 = *(const float4*)(resid + r * N + n_blk + ng + 4);
                v[0] += r0.x; v[1] += r0.y; v[2] += r0.z; v[3] += r0.w;
                v[4] += r1.x; v[5] += r1.y; v[6] += r1.z; v[7] += r1.w;
            }
            const float4 o0 = {v[0], v[1], v[2], v[3]};
            const float4 o1 = {v[4], v[5], v[6], v[7]};
            *(float4*)(out + r * N + n_blk + ng)     = o0;
            *(float4*)(out + r * N + n_blk + ng + 4) = o1;
        }
    }
}

// ---------------------------------------------------------------------------
// Fast-path fused window attention (reads materialized qkv [B,L,768]).
// One 64-thread block per (window, head).
// ---------------------------------------------------------------------------
__global__ __launch_bounds__(64) void k_attn(const float* __restrict__ qkv,
                                             const float* __restrict__ rpb, // [343,8]
                                             float* __restrict__ out,
                                             int shift)
{
    __shared__ float Ks[64][32];
    __shared__ float Vs[64][32];
    __shared__ float rp[344];
    __shared__ int   cnts[64];
    const int w    = blockIdx.x;          // b*512 + window
    const int head = blockIdx.y;
    const int b    = w >> 9;
    const int widx = w & 511;
    const int wh = widx >> 6, ww = (widx >> 3) & 7, wt = widx & 7;
    const int p  = threadIdx.x;
    const int ph = p >> 4, pw = (p >> 2) & 3, pt = p & 3;
    const int h0 = (wh * 4 + ph + shift) & 31;
    const int w0 = (ww * 4 + pw + shift) & 31;
    const int t0 = (wt * 4 + pt + shift) & 31;
    const int l  = (h0 * 32 + w0) * 32 + t0;
    const float* base = qkv + ((size_t)b * L_PER_B + l) * 768 + head * 32;

    float q[32];
    #pragma unroll
    for (int i = 0; i < 8; ++i) {
        const float4 qv = *(const float4*)(base + i * 4);
        q[i*4] = qv.x; q[i*4+1] = qv.y; q[i*4+2] = qv.z; q[i*4+3] = qv.w;
        *(float4*)&Ks[p][i*4] = *(const float4*)(base + 256 + i * 4);
        *(float4*)&Vs[p][i*4] = *(const float4*)(base + 512 + i * 4);
    }
    for (int i = p; i < 343; i += 64) rp[i] = rpb[i * 8 + head];
    const int ih = wh * 4 + ph, iw = ww * 4 + pw, it = wt * 4 + pt;
    const int rh = ih >= 30 ? 2 : (ih >= 28 ? 1 : 0);
    const int rw = iw >= 30 ? 2 : (iw >= 28 ? 1 : 0);
    const int rt = it >= 30 ? 2 : (it >= 28 ? 1 : 0);
    const int cnt = rh * 9 + rw * 3 + rt;
    cnts[p] = cnt;
    __syncthreads();

    float s[64];
    const float scale = 0.17677669529663687f;   // 1/sqrt(32)
    #pragma unroll
    for (int m = 0; m < 64; ++m) {
        float d = 0.f;
        #pragma unroll
        for (int i = 0; i < 32; ++i) d = fmaf(q[i], Ks[m][i], d);
        const int mh = m >> 4, mw = (m >> 2) & 3, mt = m & 3;
        float sc = d * scale + rp[(ph - mh + 3) * 49 + (pw - mw + 3) * 7 + (pt - mt + 3)];
        if (shift && (cnts[m] != cnt)) sc -= 100.f;
        s[m] = sc;
    }
    float mx = s[0];
    #pragma unroll
    for (int m = 1; m < 64; ++m) mx = fmaxf(mx, s[m]);
    float sum = 0.f;
    #pragma unroll
    for (int m = 0; m < 64; ++m) { s[m] = expf(s[m] - mx); sum += s[m]; }
    const float inv = 1.f / sum;
    float o[32];
    #pragma unroll
    for (int i = 0; i < 32; ++i) o[i] = 0.f;
    #pragma unroll
    for (int m = 0; m < 64; ++m) {
        const float pm = s[m] * inv;
        #pragma unroll
        for (int i = 0; i < 32; ++i) o[i] = fmaf(pm, Vs[m][i], o[i]);
    }
    float* ob = out + ((size_t)b * L_PER_B + l) * 256 + head * 32;
    #pragma unroll
    for (int i = 0; i < 8; ++i) {
        const float4 o4 = {o[i*4], o[i*4+1], o[i*4+2], o[i*4+3]};
        *(float4*)(ob + i * 4) = o4;
    }
}

// ---------------------------------------------------------------------------
// Low-memory fused attention: inline LayerNorm + on-the-fly QKV from the raw
// residual stream. One 64-thread wave per (window, head); thread p owns one
// token. Weight reads are wave-uniform (scalar-broadcast path).
// ---------------------------------------------------------------------------
__global__ __launch_bounds__(64) void k_attn_fused2(const float* __restrict__ hres, // [B*L,256]
                                                    const float* __restrict__ lg,   // [256]
                                                    const float* __restrict__ lb,   // [256]
                                                    const float* __restrict__ qkvw, // [256][768]
                                                    const float* __restrict__ qkvb, // [768]
                                                    const float* __restrict__ rpb,  // [343][8]
                                                    float* __restrict__ out,        // [B*L,256]
                                                    int shift)
{
    __shared__ float Ks[64][36];
    __shared__ float Vs[64][36];
    __shared__ float rp[344];
    __shared__ int   cnts[64];
    const int w    = blockIdx.x;
    const int head = blockIdx.y;
    const int b    = w >> 9;
    const int widx = w & 511;
    const int wh = widx >> 6, ww = (widx >> 3) & 7, wt = widx & 7;
    const int p  = threadIdx.x;
    const int ph = p >> 4, pw = (p >> 2) & 3, pt = p & 3;
    const int h0 = (wh * 4 + ph + shift) & 31;
    const int w0 = (ww * 4 + pw + shift) & 31;
    const int t0 = (wt * 4 + pt + shift) & 31;
    const int l  = (h0 * 32 + w0) * 32 + t0;

    for (int i = p; i < 343; i += 64) rp[i] = rpb[i * 8 + head];
    const int ih = wh * 4 + ph, iw = ww * 4 + pw, it = wt * 4 + pt;
    const int rh = ih >= 30 ? 2 : (ih >= 28 ? 1 : 0);
    const int rw = iw >= 30 ? 2 : (iw >= 28 ? 1 : 0);
    const int rt = it >= 30 ? 2 : (it >= 28 ? 1 : 0);
    const int cnt = rh * 9 + rw * 3 + rt;
    cnts[p] = cnt;

    const float* xrow = hres + ((size_t)b * L_PER_B + l) * 256;

    // ---- inline LN stats for this token ----
    float ssum = 0.f, ssq = 0.f;
    #pragma unroll
    for (int i = 0; i < 64; ++i) {
        const float4 v4 = *(const float4*)(xrow + i * 4);
        ssum += v4.x + v4.y + v4.z + v4.w;
        ssq  += v4.x * v4.x + v4.y * v4.y + v4.z * v4.z + v4.w * v4.w;
    }
    const float mu  = ssum * 0.00390625f;
    const float rsd = rsqrtf(fmaxf(ssq * 0.00390625f - mu * mu, 0.f) + 1e-5f);

    // ---- on-the-fly QKV for this head ----
    const float* wb = qkvw + head * 32;
    float q[32], kx[32], vx[32];
    #pragma unroll
    for (int c = 0; c < 32; ++c) {
        q[c]  = qkvb[head * 32 + c];
        kx[c] = qkvb[256 + head * 32 + c];
        vx[c] = qkvb[512 + head * 32 + c];
    }
    for (int kc = 0; kc < 8; ++kc) {
        float a[32];
        #pragma unroll
        for (int i = 0; i < 8; ++i) {
            const float4 v4 = *(const float4*)(xrow + kc * 32 + i * 4);
            const float4 g4 = *(const float4*)(lg + kc * 32 + i * 4);
            const float4 b4 = *(const float4*)(lb + kc * 32 + i * 4);
            a[i*4+0] = (v4.x - mu) * rsd * g4.x + b4.x;
            a[i*4+1] = (v4.y - mu) * rsd * g4.y + b4.y;
            a[i*4+2] = (v4.z - mu) * rsd * g4.z + b4.z;
            a[i*4+3] = (v4.w - mu) * rsd * g4.w + b4.w;
        }
        #pragma unroll 4
        for (int kk = 0; kk < 32; ++kk) {
            const float* wr = wb + (size_t)(kc * 32 + kk) * 768;  // wave-uniform
            const float av = a[kk];
            #pragma unroll
            for (int c = 0; c < 32; ++c) q[c]  = fmaf(av, wr[c],       q[c]);
            #pragma unroll
            for (int c = 0; c < 32; ++c) kx[c] = fmaf(av, wr[256 + c], kx[c]);
            #pragma unroll
            for (int c = 0; c < 32; ++c) vx[c] = fmaf(av, wr[512 + c], vx[c]);
        }
    }
    const float scale = 0.17677669529663687f;   // 1/sqrt(32)
    #pragma unroll
    for (int c = 0; c < 32; ++c) {
        q[c] *= scale;
        Ks[p][c] = kx[c];
        Vs[p][c] = vx[c];
    }
    __syncthreads();

    float s[64];
    #pragma unroll 8
    for (int m = 0; m < 64; ++m) {
        float d = 0.f;
        #pragma unroll
        for (int i = 0; i < 32; ++i) d = fmaf(q[i], Ks[m][i], d);
        const int mh = m >> 4, mw = (m >> 2) & 3, mt = m & 3;
        float sc = d + rp[(ph - mh + 3) * 49 + (pw - mw + 3) * 7 + (pt - mt + 3)];
        if (shift && (cnts[m] != cnt)) sc -= 100.f;
        s[m] = sc;
    }
    float mx = s[0];
    #pragma unroll
    for (int m = 1; m < 64; ++m) mx = fmaxf(mx, s[m]);
    float sum = 0.f;
    #pragma unroll
    for (int m = 0; m < 64; ++m) { s[m] = expf(s[m] - mx); sum += s[m]; }
    const float inv = 1.f / sum;
    float o[32];
    #pragma unroll
    for (int i = 0; i < 32; ++i) o[i] = 0.f;
    #pragma unroll 8
    for (int m = 0; m < 64; ++m) {
        const float pm = s[m] * inv;
        #pragma unroll
        for (int i = 0; i < 32; ++i) o[i] = fmaf(pm, Vs[m][i], o[i]);
    }
    float* ob = out + ((size_t)b * L_PER_B + l) * 256 + head * 32;
    #pragma unroll
    for (int i = 0; i < 8; ++i) {
        const float4 o4 = {o[i*4], o[i*4+1], o[i*4+2], o[i*4+3]};
        *(float4*)(ob + i * 4) = o4;
    }
}

// ---------------------------------------------------------------------------
// Depthwise 3x3x3 conv, channels-last on [B, L, C], SAME zero padding.
// ---------------------------------------------------------------------------
__global__ __launch_bounds__(256) void k_dwconv(const float* __restrict__ in,
                                                const float* __restrict__ w, // [256][27]
                                                float* __restrict__ out)
{
    __shared__ float wl[27][256];
    const int tid = threadIdx.x;
    for (int i = tid; i < 27 * 256; i += 256) {
        const int tap = i >> 8, c = i & 255;
        wl[tap][c] = w[c * 27 + tap];
    }
    __syncthreads();
    const int wwv = blockIdx.x, hh = blockIdx.y, b = blockIdx.z;
    const int c4 = (tid & 63) * 4;
    const int tg = tid >> 6;
    const float* ib = in + (size_t)b * L_PER_B * 256;
    float* ob = out + (size_t)b * L_PER_B * 256 + (size_t)((hh * 32 + wwv) * 32) * 256;
    for (int tt = tg * 8; tt < tg * 8 + 8; ++tt) {
        float4 acc = {0.f, 0.f, 0.f, 0.f};
        #pragma unroll
        for (int dh = -1; dh <= 1; ++dh) {
            const int h2 = hh + dh;
            if ((unsigned)h2 > 31u) continue;
            #pragma unroll
            for (int dwi = -1; dwi <= 1; ++dwi) {
                const int w2 = wwv + dwi;
                if ((unsigned)w2 > 31u) continue;
                #pragma unroll
                for (int dt = -1; dt <= 1; ++dt) {
                    const int t2 = tt + dt;
                    if ((unsigned)t2 > 31u) continue;
                    const int tap = (dh + 1) * 9 + (dwi + 1) * 3 + (dt + 1);
                    const float4 iv = *(const float4*)&ib[((size_t)(h2 * 32 + w2) * 32 + t2) * 256 + c4];
                    const float4 wv = *(const float4*)&wl[tap][c4];
                    acc.x = fmaf(iv.x, wv.x, acc.x);
                    acc.y = fmaf(iv.y, wv.y, acc.y);
                    acc.z = fmaf(iv.z, wv.z, acc.z);
                    acc.w = fmaf(iv.w, wv.w, acc.w);
                }
            }
        }
        *(float4*)&ob[(size_t)tt * 256 + c4] = acc;
    }
}

// ---------------------------------------------------------------------------
extern "C" void kernel_launch(void* const* d_in, const int* in_sizes, int n_in,
                              void* d_out, int out_size, void* d_ws, size_t ws_size,
                              hipStream_t stream)
{
    const float* x      = (const float*)d_in[0];
    const float* g1     = (const float*)d_in[1];
    const float* b1     = (const float*)d_in[2];
    const float* qkv_w  = (const float*)d_in[3];
    const float* qkv_b  = (const float*)d_in[4];
    const float* proj_w = (const float*)d_in[5];
    const float* proj_b = (const float*)d_in[6];
    const float* rpb    = (const float*)d_in[7];
    const float* g2     = (const float*)d_in[8];
    const float* b2     = (const float*)d_in[9];
    const float* fc1_w  = (const float*)d_in[10];
    const float* fc1_b  = (const float*)d_in[11];
    const float* fc2_w  = (const float*)d_in[12];
    const float* fc2_b  = (const float*)d_in[13];
    const float* dw_w   = (const float*)d_in[14];
    const float* pw_w   = (const float*)d_in[15];
    const float* pw_b   = (const float*)d_in[16];
    float* out = (float*)d_out;

    // Residual stream h lives in d_out (same shape/count); it is dead by the
    // time the final pointwise GEMM rewrites d_out.
    float* h  = out;
    float* ws = (float*)d_ws;

    const bool fast = ws_size >= (size_t)M_TOK * 1280 * sizeof(float);  // 336 MB

    k_nchw_to_nlc<<<dim3(1024, 8, 2), 256, 0, stream>>>(x, h);

    if (fast) {
        // ws: buf1 [M,256] | big [M,1024] = qkv(768)+att(256), later m1(1024)
        float* buf1 = ws;
        float* big  = ws + (size_t)M_TOK * 256;
        float* qkv  = big;
        float* att  = big + (size_t)M_TOK * 768;
        float* m1   = big;
        for (int i = 0; i < 4; ++i) {
            const int shift = (i & 1) ? 2 : 0;
            k_ln<<<M_TOK / 4, 256, 0, stream>>>(h, g1 + i * 256, b1 + i * 256, buf1);
            k_gemm<0, false, false><<<dim3(6, 512), 256, 0, stream>>>(
                buf1, qkv_w + (size_t)i * 256 * 768, qkv_b + i * 768,
                nullptr, qkv, 768, 256, nullptr, nullptr, nullptr);
            k_attn<<<dim3(1024, 8), 64, 0, stream>>>(qkv, rpb + (size_t)i * 2744, att, shift);
            k_gemm<2, false, false><<<dim3(2, 512), 256, 0, stream>>>(
                att, proj_w + (size_t)i * 65536, proj_b + i * 256,
                h, h, 256, 256, nullptr, nullptr, nullptr);
            k_ln<<<M_TOK / 4, 256, 0, stream>>>(h, g2 + i * 256, b2 + i * 256, buf1);
            k_gemm<1, false, false><<<dim3(8, 512), 256, 0, stream>>>(
                buf1, fc1_w + (size_t)i * 262144, fc1_b + i * 1024,
                nullptr, m1, 1024, 256, nullptr, nullptr, nullptr);
            k_gemm<2, false, false><<<dim3(2, 512), 256, 0, stream>>>(
                m1, fc2_w + (size_t)i * 262144, fc2_b + i * 256,
                h, h, 256, 1024, nullptr, nullptr, nullptr);
        }
        k_dwconv<<<dim3(32, 32, 2), 256, 0, stream>>>(h, dw_w, buf1);
        k_gemm<3, false, true><<<dim3(2, 512), 256, 0, stream>>>(
            buf1, pw_w, pw_b, nullptr, out, 256, 256, nullptr, nullptr, nullptr);
    } else {
        // 64 MiB path: single multi-use buffer.
        //   attention out: buf[0 .. M*256)                      (64 MB)
        //   MLP chunk:     m1c = buf[0 .. 8192*1024),  stats at +32MB (64 KB)
        //   dwconv out:    buf[0 .. M*256)                      (64 MB)
        float* buf    = ws;
        float* statsc = ws + (size_t)8192 * 1024;
        const int MC = 8192;   // MLP row chunk (M/8)
        for (int i = 0; i < 4; ++i) {
            const int shift = (i & 1) ? 2 : 0;
            k_attn_fused2<<<dim3(1024, 8), 64, 0, stream>>>(
                h, g1 + i * 256, b1 + i * 256,
                qkv_w + (size_t)i * 256 * 768, qkv_b + i * 768,
                rpb + (size_t)i * 2744, buf, shift);
            k_gemm<2, false, false><<<dim3(2, 512), 256, 0, stream>>>(
                buf, proj_w + (size_t)i * 65536, proj_b + i * 256,
                h, h, 256, 256, nullptr, nullptr, nullptr);
            for (int c = 0; c < 8; ++c) {
                float* hc = h + (size_t)c * MC * 256;
                k_lnstats<<<MC / 4, 256, 0, stream>>>(hc, statsc);
                k_gemm<1, true, false><<<dim3(8, MC / 128), 256, 0, stream>>>(
                    hc, fc1_w + (size_t)i * 262144, fc1_b + i * 1024,
                    nullptr, buf, 1024, 256, statsc, g2 + i * 256, b2 + i * 256);
                k_gemm<2, false, false><<<dim3(2, MC / 128), 256, 0, stream>>>(
                    buf, fc2_w + (size_t)i * 262144, fc2_b + i * 256,
                    hc, hc, 256, 1024, nullptr, nullptr, nullptr);
            }
        }
        k_dwconv<<<dim3(32, 32, 2), 256, 0, stream>>>(h, dw_w, buf);
        k_gemm<3, false, true><<<dim3(2, 512), 256, 0, stream>>>(
            buf, pw_w, pw_b, nullptr, out, 256, 256, nullptr, nullptr, nullptr);
    }
}

// Round 5
// 9671.040 us; speedup vs baseline: 1.3679x; 1.3679x over previous
//
#include <hip/hip_runtime.h>
#include <math.h>

#define L_PER_B 32768
#define M_TOK   65536
#define CHTOK   16384     // tokens per attention chunk: 2 batches x 8 h-planes x 1024

// ---------------------------------------------------------------------------
// x [B, C, 32,32,32]  ->  h [B, L, C]   (tokens-channels)
// ---------------------------------------------------------------------------
__global__ __launch_bounds__(256) void k_nchw_to_nlc(const float* __restrict__ x,
                                                     float* __restrict__ h)
{
    __shared__ float t[32][33];
    const int lt = blockIdx.x * 32;
    const int ct = blockIdx.y * 32;
    const int b  = blockIdx.z;
    const int li = threadIdx.x & 31;
    const int cg = threadIdx.x >> 5;
    const float* xb = x + (size_t)b * 256 * L_PER_B;
    #pragma unroll
    for (int r = 0; r < 4; ++r) {
        const int c = cg + 8 * r;
        t[c][li] = xb[(size_t)(ct + c) * L_PER_B + lt + li];
    }
    __syncthreads();
    float* hb = h + (size_t)b * L_PER_B * 256;
    #pragma unroll
    for (int r = 0; r < 4; ++r) {
        const int lrow = cg + 8 * r;
        hb[(size_t)(lt + lrow) * 256 + ct + li] = t[li][lrow];
    }
}

// ---------------------------------------------------------------------------
// LN + gather into compact chunk order. Compact row r (0..16383):
//   b = r>>13, pl = (r>>10)&7, w' = (r>>5)&31, t' = r&31   (rolled coords)
//   original token: h0=(chunk*8+pl+shift)&31, w0=(w'+shift)&31, t0=(t'+shift)&31
// ---------------------------------------------------------------------------
__global__ __launch_bounds__(256) void k_ln_gather(const float* __restrict__ h,
                                                   const float* __restrict__ g,
                                                   const float* __restrict__ b,
                                                   float* __restrict__ outc,
                                                   int chunk, int shift)
{
    const int r    = blockIdx.x * 4 + (threadIdx.x >> 6);
    const int lane = threadIdx.x & 63;
    const int bb = r >> 13, pl = (r >> 10) & 7, wq = (r >> 5) & 31, tq = r & 31;
    const int h0 = (chunk * 8 + pl + shift) & 31;
    const int w0 = (wq + shift) & 31;
    const int t0 = (tq + shift) & 31;
    const float* src = h + ((size_t)bb * L_PER_B + h0 * 1024 + w0 * 32 + t0) * 256;
    const float4 v = *(const float4*)(src + lane * 4);
    float s  = v.x + v.y + v.z + v.w;
    float s2 = v.x * v.x + v.y * v.y + v.z * v.z + v.w * v.w;
    #pragma unroll
    for (int o = 32; o > 0; o >>= 1) {
        s  += __shfl_xor(s,  o, 64);
        s2 += __shfl_xor(s2, o, 64);
    }
    const float mu = s * 0.00390625f;
    const float rs = rsqrtf(fmaxf(s2 * 0.00390625f - mu * mu, 0.f) + 1e-5f);
    const float4 gv = *(const float4*)(g + lane * 4);
    const float4 bv = *(const float4*)(b + lane * 4);
    float4 o4;
    o4.x = (v.x - mu) * rs * gv.x + bv.x;
    o4.y = (v.y - mu) * rs * gv.y + bv.y;
    o4.z = (v.z - mu) * rs * gv.z + bv.z;
    o4.w = (v.w - mu) * rs * gv.w + bv.w;
    *(float4*)(outc + (size_t)r * 256 + lane * 4) = o4;
}

// ---------------------------------------------------------------------------
// LN row statistics only: stats[2r] = mean, stats[2r+1] = rstd
// ---------------------------------------------------------------------------
__global__ __launch_bounds__(256) void k_lnstats(const float* __restrict__ x,
                                                 float* __restrict__ stats)
{
    const int row  = blockIdx.x * 4 + (threadIdx.x >> 6);
    const int lane = threadIdx.x & 63;
    const float4 v = *(const float4*)(x + (size_t)row * 256 + lane * 4);
    float s  = v.x + v.y + v.z + v.w;
    float s2 = v.x * v.x + v.y * v.y + v.z * v.z + v.w * v.w;
    #pragma unroll
    for (int o = 32; o > 0; o >>= 1) {
        s  += __shfl_xor(s,  o, 64);
        s2 += __shfl_xor(s2, o, 64);
    }
    if (lane == 0) {
        const float mu = s * 0.00390625f;
        const float rs = rsqrtf(fmaxf(s2 * 0.00390625f - mu * mu, 0.f) + 1e-5f);
        stats[2 * row]     = mu;
        stats[2 * row + 1] = rs;
    }
}

// ---------------------------------------------------------------------------
// fp32 GEMM: out[M,N] = epi(An[M,K] @ W[K,N] + bias)
// EPI 0: bias   1: bias+GELU(exact)   2: bias+residual   3: bias+ReLU,
//        store transposed to NCDHW output [B, C, L]
// LNA: A-tile load applies layernorm (stats + lg/lb)
// WT : W stored [N][K] -> read transposed
// SC : EPI2 rows scatter to token order via (wh8, shift) rolled-chunk mapping
// ---------------------------------------------------------------------------
template<int EPI, bool LNA, bool WT, bool SC>
__global__ __launch_bounds__(256) void k_gemm(const float* __restrict__ A,
                                              const float* __restrict__ W,
                                              const float* __restrict__ bias,
                                              const float* resid,   // may alias out
                                              float* out,
                                              int N, int K,
                                              const float* __restrict__ stats,
                                              const float* __restrict__ lg,
                                              const float* __restrict__ lb,
                                              int wh8, int shift)
{
    __shared__ float As[16][132];
    __shared__ float Bs[16][128];
    const int tid   = threadIdx.x;
    const int m_blk = blockIdx.y * 128;
    const int n_blk = blockIdx.x * 128;
    const int mg = (tid & 15) * 8;
    const int ng = (tid >> 4) * 8;
    float acc[8][8];
    #pragma unroll
    for (int i = 0; i < 8; ++i)
        #pragma unroll
        for (int j = 0; j < 8; ++j) acc[i][j] = 0.f;

    for (int k0 = 0; k0 < K; k0 += 16) {
        #pragma unroll
        for (int u = 0; u < 2; ++u) {
            const int f   = tid + u * 256;
            const int row = f >> 2;
            const int kq  = (f & 3) << 2;
            float4 a = *(const float4*)(A + (size_t)(m_blk + row) * K + k0 + kq);
            if constexpr (LNA) {
                const float mu  = stats[2 * (m_blk + row)];
                const float rsd = stats[2 * (m_blk + row) + 1];
                const float4 gk = *(const float4*)(lg + k0 + kq);
                const float4 bk = *(const float4*)(lb + k0 + kq);
                a.x = (a.x - mu) * rsd * gk.x + bk.x;
                a.y = (a.y - mu) * rsd * gk.y + bk.y;
                a.z = (a.z - mu) * rsd * gk.z + bk.z;
                a.w = (a.w - mu) * rsd * gk.w + bk.w;
            }
            As[kq + 0][row] = a.x;
            As[kq + 1][row] = a.y;
            As[kq + 2][row] = a.z;
            As[kq + 3][row] = a.w;
        }
        #pragma unroll
        for (int u = 0; u < 2; ++u) {
            const int f = tid + u * 256;
            if constexpr (!WT) {
                const int kk = f >> 5;
                const int nq = (f & 31) << 2;
                *(float4*)&Bs[kk][nq] = *(const float4*)(W + (size_t)(k0 + kk) * N + n_blk + nq);
            } else {
                const int n  = f >> 2;
                const int kq = (f & 3) << 2;
                const float4 wv = *(const float4*)(W + (size_t)(n_blk + n) * K + k0 + kq);
                Bs[kq + 0][n] = wv.x;
                Bs[kq + 1][n] = wv.y;
                Bs[kq + 2][n] = wv.z;
                Bs[kq + 3][n] = wv.w;
            }
        }
        __syncthreads();
        #pragma unroll
        for (int kk = 0; kk < 16; ++kk) {
            const float4 a0 = *(const float4*)&As[kk][mg];
            const float4 a1 = *(const float4*)&As[kk][mg + 4];
            const float4 b0 = *(const float4*)&Bs[kk][ng];
            const float4 b1 = *(const float4*)&Bs[kk][ng + 4];
            const float am[8] = {a0.x, a0.y, a0.z, a0.w, a1.x, a1.y, a1.z, a1.w};
            const float bn[8] = {b0.x, b0.y, b0.z, b0.w, b1.x, b1.y, b1.z, b1.w};
            #pragma unroll
            for (int i = 0; i < 8; ++i)
                #pragma unroll
                for (int j = 0; j < 8; ++j)
                    acc[i][j] = fmaf(am[i], bn[j], acc[i][j]);
        }
        __syncthreads();
    }

    if constexpr (EPI == 3) {
        const int m0    = m_blk + mg;
        const int batch = m0 >> 15;
        const int l     = m0 & 32767;
        float* ob = out + (size_t)batch * (256 * (size_t)L_PER_B) + l;
        #pragma unroll
        for (int j = 0; j < 8; ++j) {
            const int c = n_blk + ng + j;
            const float bj = bias[c];
            float4 v0, v1;
            v0.x = fmaxf(acc[0][j] + bj, 0.f); v0.y = fmaxf(acc[1][j] + bj, 0.f);
            v0.z = fmaxf(acc[2][j] + bj, 0.f); v0.w = fmaxf(acc[3][j] + bj, 0.f);
            v1.x = fmaxf(acc[4][j] + bj, 0.f); v1.y = fmaxf(acc[5][j] + bj, 0.f);
            v1.z = fmaxf(acc[6][j] + bj, 0.f); v1.w = fmaxf(acc[7][j] + bj, 0.f);
            *(float4*)(ob + (size_t)c * L_PER_B)     = v0;
            *(float4*)(ob + (size_t)c * L_PER_B + 4) = v1;
        }
    } else {
        float bj[8];
        #pragma unroll
        for (int j = 0; j < 8; ++j) bj[j] = bias[n_blk + ng + j];
        #pragma unroll
        for (int i = 0; i < 8; ++i) {
            size_t rr;
            if constexpr (SC) {
                const int r  = m_blk + mg + i;
                const int bb = r >> 13, pl = (r >> 10) & 7, wq = (r >> 5) & 31, tq = r & 31;
                const int h0 = (wh8 + pl + shift) & 31;
                const int w0 = (wq + shift) & 31;
                const int t0 = (tq + shift) & 31;
                rr = (size_t)bb * L_PER_B + h0 * 1024 + w0 * 32 + t0;
            } else {
                rr = (size_t)(m_blk + mg + i);
            }
            float v[8];
            #pragma unroll
            for (int j = 0; j < 8; ++j) v[j] = acc[i][j] + bj[j];
            if constexpr (EPI == 1) {
                #pragma unroll
                for (int j = 0; j < 8; ++j)
                    v[j] = 0.5f * v[j] * (1.f + erff(v[j] * 0.70710678118654752f));
            }
            if constexpr (EPI == 2) {
                const float4 r0 = *(const float4*)(resid + rr * N + n_blk + ng);
                const float4 r1 = *(const float4*)(resid + rr * N + n_blk + ng + 4);
                v[0] += r0.x; v[1] += r0.y; v[2] += r0.z; v[3] += r0.w;
                v[4] += r1.x; v[5] += r1.y; v[6] += r1.z; v[7] += r1.w;
            }
            const float4 o0 = {v[0], v[1], v[2], v[3]};
            const float4 o1 = {v[4], v[5], v[6], v[7]};
            *(float4*)(out + rr * N + n_blk + ng)     = o0;
            *(float4*)(out + rr * N + n_blk + ng + 4) = o1;
        }
    }
}

// ---------------------------------------------------------------------------
// Window attention over a chunk of materialized qkv (compact rolled layout).
// Block = one (window-in-chunk, head), 64 threads. blockIdx.x: b(1)|whL(1)|ww(3)|wt(3)
// ---------------------------------------------------------------------------
__global__ __launch_bounds__(64) void k_attn_c(const float* __restrict__ qkvc, // [CHTOK,768]
                                               const float* __restrict__ rpb,  // [343,8]
                                               float* __restrict__ attc,       // [CHTOK,256]
                                               int chunk, int shift)
{
    __shared__ float Ks[64][36];
    __shared__ float Vs[64][36];
    __shared__ float rp[344];
    __shared__ int   cnts[64];
    const int wid  = blockIdx.x;          // 0..255
    const int head = blockIdx.y;
    const int b   = wid >> 7;
    const int whL = (wid >> 6) & 1;
    const int ww  = (wid >> 3) & 7;
    const int wt  = wid & 7;
    const int p  = threadIdx.x;
    const int ph = p >> 4, pw = (p >> 2) & 3, pt = p & 3;
    const int pl = whL * 4 + ph;
    const int r  = b * 8192 + pl * 1024 + (ww * 4 + pw) * 32 + wt * 4 + pt;
    const float* base = qkvc + (size_t)r * 768 + head * 32;

    float q[32];
    #pragma unroll
    for (int i = 0; i < 8; ++i) {
        const float4 qv = *(const float4*)(base + i * 4);
        q[i*4] = qv.x; q[i*4+1] = qv.y; q[i*4+2] = qv.z; q[i*4+3] = qv.w;
        *(float4*)&Ks[p][i*4] = *(const float4*)(base + 256 + i * 4);
        *(float4*)&Vs[p][i*4] = *(const float4*)(base + 512 + i * 4);
    }
    for (int i = p; i < 343; i += 64) rp[i] = rpb[i * 8 + head];
    const int ih = (chunk * 2 + whL) * 4 + ph, iw = ww * 4 + pw, it = wt * 4 + pt;
    const int rh = ih >= 30 ? 2 : (ih >= 28 ? 1 : 0);
    const int rw = iw >= 30 ? 2 : (iw >= 28 ? 1 : 0);
    const int rt = it >= 30 ? 2 : (it >= 28 ? 1 : 0);
    const int cnt = rh * 9 + rw * 3 + rt;
    cnts[p] = cnt;
    __syncthreads();

    float s[64];
    const float scale = 0.17677669529663687f;   // 1/sqrt(32)
    #pragma unroll
    for (int m = 0; m < 64; ++m) {
        float d = 0.f;
        #pragma unroll
        for (int i = 0; i < 32; ++i) d = fmaf(q[i], Ks[m][i], d);
        const int mh = m >> 4, mw = (m >> 2) & 3, mt = m & 3;
        float sc = d * scale + rp[(ph - mh + 3) * 49 + (pw - mw + 3) * 7 + (pt - mt + 3)];
        if (shift && (cnts[m] != cnt)) sc -= 100.f;
        s[m] = sc;
    }
    float mx = s[0];
    #pragma unroll
    for (int m = 1; m < 64; ++m) mx = fmaxf(mx, s[m]);
    float sum = 0.f;
    #pragma unroll
    for (int m = 0; m < 64; ++m) { s[m] = expf(s[m] - mx); sum += s[m]; }
    const float inv = 1.f / sum;
    float o[32];
    #pragma unroll
    for (int i = 0; i < 32; ++i) o[i] = 0.f;
    #pragma unroll
    for (int m = 0; m < 64; ++m) {
        const float pm = s[m] * inv;
        #pragma unroll
        for (int i = 0; i < 32; ++i) o[i] = fmaf(pm, Vs[m][i], o[i]);
    }
    float* ob = attc + (size_t)r * 256 + head * 32;
    #pragma unroll
    for (int i = 0; i < 8; ++i) {
        const float4 o4 = {o[i*4], o[i*4+1], o[i*4+2], o[i*4+3]};
        *(float4*)(ob + i * 4) = o4;
    }
}

// ---------------------------------------------------------------------------
// Depthwise 3x3x3 conv, channels-last on [B, L, C], SAME zero padding.
// ---------------------------------------------------------------------------
__global__ __launch_bounds__(256) void k_dwconv(const float* __restrict__ in,
                                                const float* __restrict__ w, // [256][27]
                                                float* __restrict__ out)
{
    __shared__ float wl[27][256];
    const int tid = threadIdx.x;
    for (int i = tid; i < 27 * 256; i += 256) {
        const int tap = i >> 8, c = i & 255;
        wl[tap][c] = w[c * 27 + tap];
    }
    __syncthreads();
    const int wwv = blockIdx.x, hh = blockIdx.y, b = blockIdx.z;
    const int c4 = (tid & 63) * 4;
    const int tg = tid >> 6;
    const float* ib = in + (size_t)b * L_PER_B * 256;
    float* ob = out + (size_t)b * L_PER_B * 256 + (size_t)((hh * 32 + wwv) * 32) * 256;
    for (int tt = tg * 8; tt < tg * 8 + 8; ++tt) {
        float4 acc = {0.f, 0.f, 0.f, 0.f};
        #pragma unroll
        for (int dh = -1; dh <= 1; ++dh) {
            const int h2 = hh + dh;
            if ((unsigned)h2 > 31u) continue;
            #pragma unroll
            for (int dwi = -1; dwi <= 1; ++dwi) {
                const int w2 = wwv + dwi;
                if ((unsigned)w2 > 31u) continue;
                #pragma unroll
                for (int dt = -1; dt <= 1; ++dt) {
                    const int t2 = tt + dt;
                    if ((unsigned)t2 > 31u) continue;
                    const int tap = (dh + 1) * 9 + (dwi + 1) * 3 + (dt + 1);
                    const float4 iv = *(const float4*)&ib[((size_t)(h2 * 32 + w2) * 32 + t2) * 256 + c4];
                    const float4 wv = *(const float4*)&wl[tap][c4];
                    acc.x = fmaf(iv.x, wv.x, acc.x);
                    acc.y = fmaf(iv.y, wv.y, acc.y);
                    acc.z = fmaf(iv.z, wv.z, acc.z);
                    acc.w = fmaf(iv.w, wv.w, acc.w);
                }
            }
        }
        *(float4*)&ob[(size_t)tt * 256 + c4] = acc;
    }
}

// ---------------------------------------------------------------------------
extern "C" void kernel_launch(void* const* d_in, const int* in_sizes, int n_in,
                              void* d_out, int out_size, void* d_ws, size_t ws_size,
                              hipStream_t stream)
{
    const float* x      = (const float*)d_in[0];
    const float* g1     = (const float*)d_in[1];
    const float* b1     = (const float*)d_in[2];
    const float* qkv_w  = (const float*)d_in[3];
    const float* qkv_b  = (const float*)d_in[4];
    const float* proj_w = (const float*)d_in[5];
    const float* proj_b = (const float*)d_in[6];
    const float* rpb    = (const float*)d_in[7];
    const float* g2     = (const float*)d_in[8];
    const float* b2     = (const float*)d_in[9];
    const float* fc1_w  = (const float*)d_in[10];
    const float* fc1_b  = (const float*)d_in[11];
    const float* fc2_w  = (const float*)d_in[12];
    const float* fc2_b  = (const float*)d_in[13];
    const float* dw_w   = (const float*)d_in[14];
    const float* pw_w   = (const float*)d_in[15];
    const float* pw_b   = (const float*)d_in[16];
    float* out = (float*)d_out;

    // h (residual stream) lives in d_out; dead before final GEMM rewrites it.
    // ws layout (64 MiB budget):
    //  attention phase: qkvc [CHTOK,768] @ 0 (48 MiB) | lnc/attc [CHTOK,256] @ +12582912 fl (16 MiB)
    //  MLP phase:       m1c [8192,1024] @ 0 (32 MiB)  | stats [2*M] @ +12582912 fl (512 KiB)
    //  tail:            dwconv out [M,256] @ 0 (64 MiB)
    float* h     = out;
    float* ws    = (float*)d_ws;
    float* qkvc  = ws;
    float* lnc   = ws + (size_t)12582912;   // == CHTOK*768
    float* attc  = lnc;
    float* m1c   = ws;
    float* stats = ws + (size_t)12582912;

    k_nchw_to_nlc<<<dim3(1024, 8, 2), 256, 0, stream>>>(x, h);

    for (int i = 0; i < 4; ++i) {
        const int shift = (i & 1) ? 2 : 0;
        // ---- attention in 4 chunks of 2 window-rows (8 h-planes) ----
        for (int c = 0; c < 4; ++c) {
            k_ln_gather<<<CHTOK / 4, 256, 0, stream>>>(h, g1 + i * 256, b1 + i * 256,
                                                       lnc, c, shift);
            k_gemm<0, false, false, false><<<dim3(6, CHTOK / 128), 256, 0, stream>>>(
                lnc, qkv_w + (size_t)i * 196608, qkv_b + i * 768,
                nullptr, qkvc, 768, 256, nullptr, nullptr, nullptr, 0, 0);
            k_attn_c<<<dim3(256, 8), 64, 0, stream>>>(qkvc, rpb + (size_t)i * 2744,
                                                      attc, c, shift);
            k_gemm<2, false, false, true><<<dim3(2, CHTOK / 128), 256, 0, stream>>>(
                attc, proj_w + (size_t)i * 65536, proj_b + i * 256,
                h, h, 256, 256, nullptr, nullptr, nullptr, c * 8, shift);
        }
        // ---- MLP: one full-M stats pass + 8 row chunks ----
        k_lnstats<<<M_TOK / 4, 256, 0, stream>>>(h, stats);
        for (int c2 = 0; c2 < 8; ++c2) {
            float* hc = h + (size_t)c2 * 8192 * 256;
            k_gemm<1, true, false, false><<<dim3(8, 64), 256, 0, stream>>>(
                hc, fc1_w + (size_t)i * 262144, fc1_b + i * 1024,
                nullptr, m1c, 1024, 256, stats + (size_t)c2 * 16384,
                g2 + i * 256, b2 + i * 256, 0, 0);
            k_gemm<2, false, false, false><<<dim3(2, 64), 256, 0, stream>>>(
                m1c, fc2_w + (size_t)i * 262144, fc2_b + i * 256,
                hc, hc, 256, 1024, nullptr, nullptr, nullptr, 0, 0);
        }
    }

    k_dwconv<<<dim3(32, 32, 2), 256, 0, stream>>>(h, dw_w, ws);
    k_gemm<3, false, true, false><<<dim3(2, 512), 256, 0, stream>>>(
        ws, pw_w, pw_b, nullptr, out, 256, 256, nullptr, nullptr, nullptr, 0, 0);
}